// Round 3
// baseline (1132.168 us; speedup 1.0000x reference)
//
#include <hip/hip_runtime.h>
#include <hip/hip_cooperative_groups.h>
#include <math.h>

namespace cg = cooperative_groups;

#define NPIX 16384      // H*W
#define CCH  512        // channels
#define MS   262144     // 512*512

typedef unsigned short u16;
typedef unsigned int u32;
typedef __attribute__((ext_vector_type(8))) short bf16x8;   // 8 bf16 = 4 VGPR
typedef __attribute__((ext_vector_type(4))) float f32x4;

__device__ __forceinline__ u16 f2bf(float f) {
  u32 u = __builtin_bit_cast(u32, f);
  u += 0x7fffu + ((u >> 16) & 1u);    // round-to-nearest-even
  return (u16)(u >> 16);
}
__device__ __forceinline__ float b2f(u16 h) {
  u32 u = ((u32)h) << 16;
  return __builtin_bit_cast(float, u);
}

typedef const __attribute__((address_space(1))) u32* gp_t;
typedef __attribute__((address_space(3))) u32* lp_t;
__device__ __forceinline__ void gl_lds16(const void* g, void* l) {
  __builtin_amdgcn_global_load_lds((gp_t)g, (lp_t)l, 16, 0, 0);
}

// ---- Kt=128 staged tile, XOR chunk swizzle (LDS row = 128 bf16 = 16x16B chunks)
__device__ __forceinline__ void stage4(const u16* tile, size_t stride, int rl,
                                       int k0, u16* lds, int lane) {
  int lr = lane >> 4;                               // 4 rows per instruction
  int cg2 = (lane & 15) ^ ((rl + lr) & 15);         // swizzled global chunk
  gl_lds16(tile + (size_t)(rl + lr) * stride + k0 + cg2 * 8,
           lds + (size_t)rl * 128);
}
__device__ __forceinline__ bf16x8 fragld(const u16* lds, int row, int cl) {
  return *(const bf16x8*)&lds[(size_t)row * 128 + (size_t)((cl ^ (row & 15)) << 3)];
}

// ---- Kt=64 variants (LDS row = 64 bf16 = 8x16B chunks); 8 rows per gl_lds16
__device__ __forceinline__ void stage8_64(const u16* tile, size_t stride, int rl,
                                          int k0, u16* lds, int lane) {
  int lr = lane >> 3;                               // 8 rows per instruction
  int cg2 = (lane & 7) ^ ((rl + lr) & 7);           // swizzled global chunk
  gl_lds16(tile + (size_t)(rl + lr) * stride + k0 + cg2 * 8,
           lds + (size_t)rl * 64);
}
__device__ __forceinline__ bf16x8 fragld64(const u16* lds, int row, int cl) {
  return *(const bf16x8*)&lds[(size_t)row * 64 + (size_t)((cl ^ (row & 7)) << 3)];
}

// ================= prep: one pass over X -> colsums, fct (bf16 [c][n]), fcb (bf16 [n][c])
__global__ __launch_bounds__(256) void prep_k(const float* __restrict__ Xc,
                                              const float* __restrict__ Xs,
                                              float* __restrict__ sums,
                                              u16* __restrict__ fct,
                                              u16* __restrict__ fcb) {
  int b = blockIdx.z;
  const float* X = b ? Xs : Xc;
  u16* outT = fct + (size_t)b * ((size_t)CCH * NPIX);
  __shared__ float T[64][65];
  __shared__ float red2[64][4];
  int n0 = blockIdx.x * 64, c0 = blockIdx.y * 64;
  int t = threadIdx.x;
  int cr = t & 15, nr = t >> 4;
  #pragma unroll
  for (int rr = 0; rr < 4; ++rr) {
    int n = nr + rr * 16;
    float4 v = *(const float4*)&X[(size_t)(n0 + n) * CCH + c0 + cr * 4];
    T[n][cr * 4 + 0] = v.x;
    T[n][cr * 4 + 1] = v.y;
    T[n][cr * 4 + 2] = v.z;
    T[n][cr * 4 + 3] = v.w;
    if (b == 0) {
      ushort4 q;
      q.x = f2bf(v.x); q.y = f2bf(v.y); q.z = f2bf(v.z); q.w = f2bf(v.w);
      *(ushort4*)&fcb[(size_t)(n0 + n) * CCH + c0 + cr * 4] = q;
    }
  }
  __syncthreads();
  int cl = t >> 2, np = (t & 3) * 16;
  size_t obase = (size_t)(c0 + cl) * NPIX + n0 + np;
  float s = 0.f;
  #pragma unroll
  for (int i = 0; i < 16; i += 4) {
    float v0 = T[np + i + 0][cl], v1 = T[np + i + 1][cl];
    float v2 = T[np + i + 2][cl], v3 = T[np + i + 3][cl];
    s += v0 + v1 + v2 + v3;
    ushort4 o;
    o.x = f2bf(v0); o.y = f2bf(v1); o.z = f2bf(v2); o.w = f2bf(v3);
    *(ushort4*)&outT[obase + i] = o;
  }
  red2[cl][t & 3] = s;
  __syncthreads();
  if (t < 64) {
    float cs = red2[t][0] + red2[t][1] + red2[t][2] + red2[t][3];
    atomicAdd(&sums[b * CCH + c0 + t], cs);
  }
}

// ================= Gram partials: 16 pairs x 16 kc x 2 batches = 512 blocks = 2/CU
__global__ __launch_bounds__(256, 2) void gram_part(const u16* __restrict__ fct,
                                                    float* __restrict__ Gp) {
  int kc = blockIdx.x;               // 0..15, K chunk of 1024
  int pair = blockIdx.y;             // 0..15
  int b = blockIdx.z;
  int bi = pair >> 2, bj = pair & 3;
  const u16* Xb = fct + (size_t)b * ((size_t)CCH * NPIX);
  __shared__ u16 As[2][128 * 64];    // 2 x 16 KB
  __shared__ u16 Bs[2][128 * 64];    // 2 x 16 KB
  int tid = threadIdx.x, w = tid >> 6, lane = tid & 63;
  int qm = w & 1, qn = w >> 1;
  const u16* ssrc = (w < 2) ? Xb + (size_t)(bi * 128) * NPIX
                            : Xb + (size_t)(bj * 128) * NPIX;
  int rbase = (w & 1) * 64;
  f32x4 acc[4][4];
  #pragma unroll
  for (int t = 0; t < 4; ++t)
    #pragma unroll
    for (int u = 0; u < 4; ++u) acc[t][u] = (f32x4)(0.f);

  #pragma unroll
  for (int i = 0; i < 8; ++i)
    stage8_64(ssrc, NPIX, rbase + i * 8, kc * 1024, (w < 2) ? As[0] : Bs[0], lane);
  __syncthreads();

  for (int st = 0; st < 16; ++st) {
    int cur = st & 1;
    if (st < 15) {
      int k0n = kc * 1024 + (st + 1) * 64;
      #pragma unroll
      for (int i = 0; i < 8; ++i)
        stage8_64(ssrc, NPIX, rbase + i * 8, k0n,
                  (w < 2) ? As[cur ^ 1] : Bs[cur ^ 1], lane);
    }
    #pragma unroll
    for (int s = 0; s < 2; ++s) {
      int cl = s * 4 + (lane >> 4);
      bf16x8 a[4], bb[4];
      #pragma unroll
      for (int t = 0; t < 4; ++t) a[t] = fragld64(As[cur], qm * 64 + t * 16 + (lane & 15), cl);
      #pragma unroll
      for (int u = 0; u < 4; ++u) bb[u] = fragld64(Bs[cur], qn * 64 + u * 16 + (lane & 15), cl);
      #pragma unroll
      for (int t = 0; t < 4; ++t)
        #pragma unroll
        for (int u = 0; u < 4; ++u)
          acc[t][u] = __builtin_amdgcn_mfma_f32_16x16x32_bf16(a[t], bb[u], acc[t][u], 0, 0, 0);
    }
    __syncthreads();
  }
  size_t tbase = ((size_t)(b * 16 + kc) * 16 + pair) * 16384;
  #pragma unroll
  for (int t = 0; t < 4; ++t) {
    int row0 = qm * 64 + t * 16 + (lane >> 4) * 4;
    #pragma unroll
    for (int u = 0; u < 4; ++u) {
      int col = qn * 64 + u * 16 + (lane & 15);
      #pragma unroll
      for (int r4 = 0; r4 < 4; ++r4)
        Gp[tbase + (size_t)(row0 + r4) * 128 + col] = acc[t][u][r4];
    }
  }
}

// ================= cooperative-chain tile workers (64x64 tile, Kt=64 dbuf) =========
// plain: D = diag*I + scale*(A @ B^T); LDS: As@0/4096, Bs@8192/12288 (u16 offs)
__device__ __forceinline__ void mm_step(const u16* A, const u16* B, void* D,
                                        float scale, float diag, int outFp32,
                                        u16* smem, int tid, int bi, int bj) {
  int w = tid >> 6, lane = tid & 63;
  int qm = w & 1, qn = w >> 1;
  const u16* ssrc = (w < 2) ? A + (size_t)(bi * 64) * CCH
                            : B + (size_t)(bj * 64) * CCH;
  int rbase = (w & 1) * 32;
  u16* sbase = (w < 2) ? smem : smem + 8192;
  f32x4 acc[2][2];
  #pragma unroll
  for (int t = 0; t < 2; ++t)
    #pragma unroll
    for (int u = 0; u < 2; ++u) acc[t][u] = (f32x4)(0.f);

  #pragma unroll
  for (int i = 0; i < 4; ++i) stage8_64(ssrc, CCH, rbase + i * 8, 0, sbase, lane);
  __syncthreads();
  for (int st = 0; st < 8; ++st) {
    int cur = st & 1;
    if (st < 7) {
      u16* sdst = sbase + (cur ^ 1) * 4096;
      #pragma unroll
      for (int i = 0; i < 4; ++i) stage8_64(ssrc, CCH, rbase + i * 8, (st + 1) * 64, sdst, lane);
    }
    u16* Ac = smem + cur * 4096;
    u16* Bc = smem + 8192 + cur * 4096;
    #pragma unroll
    for (int s = 0; s < 2; ++s) {
      int cl = s * 4 + (lane >> 4);
      bf16x8 a[2], bb[2];
      #pragma unroll
      for (int t = 0; t < 2; ++t) a[t] = fragld64(Ac, qm * 32 + t * 16 + (lane & 15), cl);
      #pragma unroll
      for (int u = 0; u < 2; ++u) bb[u] = fragld64(Bc, qn * 32 + u * 16 + (lane & 15), cl);
      #pragma unroll
      for (int t = 0; t < 2; ++t)
        #pragma unroll
        for (int u = 0; u < 2; ++u)
          acc[t][u] = __builtin_amdgcn_mfma_f32_16x16x32_bf16(a[t], bb[u], acc[t][u], 0, 0, 0);
    }
    __syncthreads();
  }
  #pragma unroll
  for (int t = 0; t < 2; ++t) {
    int row0 = bi * 64 + qm * 32 + t * 16 + (lane >> 4) * 4;
    #pragma unroll
    for (int u = 0; u < 2; ++u) {
      int col = bj * 64 + qn * 32 + u * 16 + (lane & 15);
      #pragma unroll
      for (int r4 = 0; r4 < 4; ++r4) {
        float v = scale * acc[t][u][r4];
        if (row0 + r4 == col) v += diag;
        size_t o = (size_t)(row0 + r4) * CCH + col;
        if (outFp32) ((float*)D)[o] = v;
        else ((u16*)D)[o] = f2bf(v);
      }
    }
  }
}

// split: uses full 64 KB; array a in {Ah,Al,Bh,Bl} at a*8192 + cur*4096
__device__ __forceinline__ void mms_step(const u16* Ah, const u16* Al,
                                         const u16* Bh, const u16* Bl,
                                         const u16* Eh, const u16* El, float beta,
                                         u16* Dh, u16* Dl, float* D32, u16* Db,
                                         float scale, u16* smem, int tid, int bi, int bj) {
  int w = tid >> 6, lane = tid & 63;
  int qm = w & 1, qn = w >> 1;
  const u16* sp = (w == 0) ? Ah : (w == 1) ? Al : (w == 2) ? Bh : Bl;
  const u16* ssrc = sp + (size_t)(((w < 2) ? bi : bj) * 64) * CCH;
  u16* sbase = smem + w * 8192;
  f32x4 acc[2][2];
  #pragma unroll
  for (int t = 0; t < 2; ++t)
    #pragma unroll
    for (int u = 0; u < 2; ++u) acc[t][u] = (f32x4)(0.f);

  #pragma unroll
  for (int i = 0; i < 8; ++i) stage8_64(ssrc, CCH, i * 8, 0, sbase, lane);
  __syncthreads();
  for (int st = 0; st < 8; ++st) {
    int cur = st & 1;
    if (st < 7) {
      u16* sdst = sbase + (cur ^ 1) * 4096;
      #pragma unroll
      for (int i = 0; i < 8; ++i) stage8_64(ssrc, CCH, i * 8, (st + 1) * 64, sdst, lane);
    }
    u16* Ach = smem + cur * 4096;
    u16* Acl = smem + 8192 + cur * 4096;
    u16* Bch = smem + 16384 + cur * 4096;
    u16* Bcl = smem + 24576 + cur * 4096;
    #pragma unroll
    for (int s = 0; s < 2; ++s) {
      int cl = s * 4 + (lane >> 4);
      bf16x8 ah[2], al[2], bh[2], bl[2];
      #pragma unroll
      for (int t = 0; t < 2; ++t) {
        int row = qm * 32 + t * 16 + (lane & 15);
        ah[t] = fragld64(Ach, row, cl);
        al[t] = fragld64(Acl, row, cl);
      }
      #pragma unroll
      for (int u = 0; u < 2; ++u) {
        int row = qn * 32 + u * 16 + (lane & 15);
        bh[u] = fragld64(Bch, row, cl);
        bl[u] = fragld64(Bcl, row, cl);
      }
      #pragma unroll
      for (int t = 0; t < 2; ++t)
        #pragma unroll
        for (int u = 0; u < 2; ++u) {
          acc[t][u] = __builtin_amdgcn_mfma_f32_16x16x32_bf16(ah[t], bh[u], acc[t][u], 0, 0, 0);
          acc[t][u] = __builtin_amdgcn_mfma_f32_16x16x32_bf16(ah[t], bl[u], acc[t][u], 0, 0, 0);
          acc[t][u] = __builtin_amdgcn_mfma_f32_16x16x32_bf16(al[t], bh[u], acc[t][u], 0, 0, 0);
        }
    }
    __syncthreads();
  }
  #pragma unroll
  for (int t = 0; t < 2; ++t) {
    int row0 = bi * 64 + qm * 32 + t * 16 + (lane >> 4) * 4;
    #pragma unroll
    for (int u = 0; u < 2; ++u) {
      int col = bj * 64 + qn * 32 + u * 16 + (lane & 15);
      #pragma unroll
      for (int r4 = 0; r4 < 4; ++r4) {
        size_t o = (size_t)(row0 + r4) * CCH + col;
        float v = scale * acc[t][u][r4];
        if (beta != 0.f) v += beta * (b2f(Eh[o]) + b2f(El[o]));
        if (D32) D32[o] = v;
        if (Dh) {
          u16 hh = f2bf(v);
          Dh[o] = hh;
          Dl[o] = f2bf(v - b2f(hh));
        }
        if (Db) Db[o] = f2bf(v);
      }
    }
  }
}

// ================= cooperative persistent kernel: greduce .. mconst (16 steps)
struct NSArgs {
  const float* Gp; const float* sums;
  float* cov; float* rowsum; float* snorm; float* coef; float* mconst; float* Zf;
  u16 *Anh, *Anl, *Y1, *Ya, *Z0, *Z1, *Tb, *Zfsh, *Zfsl;
  u16 *Ph, *Pl, *Qh, *Ql, *Zrsh, *Zrsl, *W2h, *W2l, *Mb;
};

__global__ __launch_bounds__(256, 2) void ns_chain(NSArgs a) {
  cg::grid_group grid = cg::this_grid();
  __shared__ u16 smem[32768];            // 64 KB, re-purposed per step
  float* redf = (float*)smem;
  int tid = threadIdx.x, bid = blockIdx.x, nb = gridDim.x;

  // ---- step 0: reduce Gram partials -> cov, rowsum(|.|)
  for (int it = 0; it < 4; ++it) {
    int idx = (bid + it * nb) * 256 + tid;
    int b = idx >> 18, ij = idx & (MS - 1);
    int i = ij >> 9, j = ij & 511;
    int pair = ((i >> 7) << 2) | (j >> 7);
    int lij = ((i & 127) << 7) | (j & 127);
    size_t base = ((size_t)(b * 16) * 16 + pair) * 16384 + lij;
    float g = 0.f;
    #pragma unroll
    for (int kc = 0; kc < 16; ++kc) g += a.Gp[base + (size_t)kc * (16 * 16384)];
    const float* s = a.sums + b * CCH;
    float v = (g - s[i] * s[j] * (1.f / (float)NPIX)) * (1.f / (float)(NPIX - 1));
    if (i == j) v += 1e-8f;
    a.cov[idx] = v;
    __syncthreads();
    redf[tid] = fabsf(v);
    __syncthreads();
    for (int st = 128; st > 0; st >>= 1) {
      if (tid < st) redf[tid] += redf[tid + st];
      __syncthreads();
    }
    if (tid == 0) atomicAdd(&a.rowsum[b * CCH + i], redf[0]);
  }
  grid.sync();

  // ---- step 1: norms + An split + Z0 init
  {
    float m = fmaxf(a.rowsum[tid], a.rowsum[tid + 256]);
    redf[tid] = m; __syncthreads();
    for (int s = 128; s > 0; s >>= 1) {
      if (tid < s) redf[tid] = fmaxf(redf[tid], redf[tid + s]);
      __syncthreads();
    }
    float snc = redf[0]; __syncthreads();
    m = fmaxf(a.rowsum[512 + tid], a.rowsum[768 + tid]);
    redf[tid] = m; __syncthreads();
    for (int s = 128; s > 0; s >>= 1) {
      if (tid < s) redf[tid] = fmaxf(redf[tid], redf[tid + s]);
      __syncthreads();
    }
    float sns = redf[0];
    if (bid == 0 && tid == 0) {
      a.snorm[0] = snc; a.snorm[1] = sns;
      a.coef[0] = 0.8f * sqrtf(sns / snc);
    }
    for (int it = 0; it < 4; ++it) {
      int idx = (bid + it * nb) * 256 + tid;
      int b = idx >> 18, ij = idx & (MS - 1);
      int diag = (ij >> 9) == (ij & 511);
      float av = a.cov[idx] * (b ? 1.f / sns : 1.f / snc);
      u16 hi = f2bf(av);
      a.Anh[idx] = hi;
      a.Anl[idx] = f2bf(av - b2f(hi));
      a.Z0[idx] = f2bf((diag ? 3.f - av : -av) * 0.70710678f);
    }
  }
  grid.sync();

  // ---- NS matmul chain (64x64 tiles; tile id t: z = t>>6, bi=(t>>3)&7, bj=t&7)
  #define TILE_IDX int z = t >> 6, r = t & 63, bi = r >> 3, bj = r & 7; (void)z;

  { int t = bid; if (t < 128) { TILE_IDX   // Y1 = An @ Z0^T
      mm_step(a.Anh + (size_t)z * MS, a.Z0 + (size_t)z * MS, a.Y1 + (size_t)z * MS,
              1.f, 0.f, 0, smem, tid, bi, bj); } }
  grid.sync();
  { int t = bid; if (t < 128) { TILE_IDX   // T0 = 3I - Z0 @ Y1^T
      mm_step(a.Z0 + (size_t)z * MS, a.Y1 + (size_t)z * MS, a.Tb + (size_t)z * MS,
              -1.f, 3.f, 0, smem, tid, bi, bj); } }
  grid.sync();
  { int t = bid; if (t < 256) { TILE_IDX   // Ya = Y1@T0/2 ; Z1 = T0@Z0/2
      const u16 *A, *B; u16* D;
      if (z < 2) { A = a.Y1 + (size_t)z * MS; B = a.Tb + (size_t)z * MS; D = a.Ya + (size_t)z * MS; }
      else { A = a.Tb + (size_t)(z - 2) * MS; B = a.Z0 + (size_t)(z - 2) * MS; D = a.Z1 + (size_t)(z - 2) * MS; }
      mm_step(A, B, D, 0.5f, 0.f, 0, smem, tid, bi, bj); } }
  grid.sync();
  { int t = bid; if (t < 128) { TILE_IDX   // T1 = 3I - Z1 @ Ya^T
      mm_step(a.Z1 + (size_t)z * MS, a.Ya + (size_t)z * MS, a.Tb + (size_t)z * MS,
              -1.f, 3.f, 0, smem, tid, bi, bj); } }
  grid.sync();
  { int t = bid; if (t < 256) { TILE_IDX   // Y1 = Ya@T1/2 ; Z0 = T1@Z1/2
      const u16 *A, *B; u16* D;
      if (z < 2) { A = a.Ya + (size_t)z * MS; B = a.Tb + (size_t)z * MS; D = a.Y1 + (size_t)z * MS; }
      else { A = a.Tb + (size_t)(z - 2) * MS; B = a.Z1 + (size_t)(z - 2) * MS; D = a.Z0 + (size_t)(z - 2) * MS; }
      mm_step(A, B, D, 0.5f, 0.f, 0, smem, tid, bi, bj); } }
  grid.sync();
  { int t = bid; if (t < 128) { TILE_IDX   // T2 = 3I - Z0 @ Y1^T
      mm_step(a.Z0 + (size_t)z * MS, a.Y1 + (size_t)z * MS, a.Tb + (size_t)z * MS,
              -1.f, 3.f, 0, smem, tid, bi, bj); } }
  grid.sync();
  { int t = bid; if (t < 128) { TILE_IDX   // Zf = T2 @ Z0 / 2  (fp32)
      mm_step(a.Tb + (size_t)z * MS, a.Z0 + (size_t)z * MS, a.Zf + (size_t)z * MS,
              0.5f, 0.f, 1, smem, tid, bi, bj); } }
  grid.sync();
  // ---- symmetrize + split Zf -> Zfsh/Zfsl
  for (int it = 0; it < 4; ++it) {
    int q = (bid + it * nb) * 256 + tid;
    int b = q >> 18, ij = q & (MS - 1);
    int i = ij >> 9, j = ij & 511;
    size_t base = (size_t)b * MS;
    float v = 0.5f * (a.Zf[base + ij] + a.Zf[base + (size_t)j * CCH + i]);
    u16 hh = f2bf(v);
    a.Zfsh[base + ij] = hh;
    a.Zfsl[base + ij] = f2bf(v - b2f(hh));
  }
  grid.sync();
  { int t = bid; if (t < 256) { TILE_IDX   // P = Zfs@An ; Q = Zfs@Zfs
      const u16 *Ah, *Al, *Bh, *Bl; u16 *Dh, *Dl;
      if (z < 2) { Ah = a.Zfsh + (size_t)z * MS; Al = a.Zfsl + (size_t)z * MS;
                   Bh = a.Anh + (size_t)z * MS;  Bl = a.Anl + (size_t)z * MS;
                   Dh = a.Ph + (size_t)z * MS;   Dl = a.Pl + (size_t)z * MS; }
      else { int zz = z - 2;
             Ah = a.Zfsh + (size_t)zz * MS; Al = a.Zfsl + (size_t)zz * MS;
             Bh = a.Zfsh + (size_t)zz * MS; Bl = a.Zfsl + (size_t)zz * MS;
             Dh = a.Qh + (size_t)zz * MS;   Dl = a.Ql + (size_t)zz * MS; }
      mms_step(Ah, Al, Bh, Bl, (const u16*)0, (const u16*)0, 0.f,
               Dh, Dl, (float*)0, (u16*)0, 1.f, smem, tid, bi, bj); } }
  grid.sync();
  { int t = bid; if (t < 128) { TILE_IDX   // Zr = 1.5 Zfs - 0.5 P@Q  (fp32 -> Zf)
      mms_step(a.Ph + (size_t)z * MS, a.Pl + (size_t)z * MS,
               a.Qh + (size_t)z * MS, a.Ql + (size_t)z * MS,
               a.Zfsh + (size_t)z * MS, a.Zfsl + (size_t)z * MS, 1.5f,
               (u16*)0, (u16*)0, a.Zf + (size_t)z * MS, (u16*)0,
               -0.5f, smem, tid, bi, bj); } }
  grid.sync();
  // ---- symmetrize + split Zr -> Zrsh/Zrsl
  for (int it = 0; it < 4; ++it) {
    int q = (bid + it * nb) * 256 + tid;
    int b = q >> 18, ij = q & (MS - 1);
    int i = ij >> 9, j = ij & 511;
    size_t base = (size_t)b * MS;
    float v = 0.5f * (a.Zf[base + ij] + a.Zf[base + (size_t)j * CCH + i]);
    u16 hh = f2bf(v);
    a.Zrsh[base + ij] = hh;
    a.Zrsl[base + ij] = f2bf(v - b2f(hh));
  }
  grid.sync();
  { int t = bid; if (t < 64) { TILE_IDX    // W2 = An_s @ Zrs_s (split out)
      mms_step(a.Anh + MS, a.Anl + MS, a.Zrsh + MS, a.Zrsl + MS,
               (const u16*)0, (const u16*)0, 0.f,
               a.W2h, a.W2l, (float*)0, (u16*)0, 1.f, smem, tid, bi, bj); } }
  grid.sync();
  { int t = bid; if (t < 64) { TILE_IDX    // M = coef * W2 @ Zrs_c (bf16)
      float sc = a.coef[0];
      mms_step(a.W2h, a.W2l, a.Zrsh, a.Zrsl,
               (const u16*)0, (const u16*)0, 0.f,
               (u16*)0, (u16*)0, (float*)0, a.Mb, sc, smem, tid, bi, bj); } }
  grid.sync();
  // ---- mconst[c] = (0.8*ssum[c] - (M @ csum)[c]) / N
  if (bid < 64) {
    int c = bid * 8 + (tid >> 5);
    int l = tid & 31;
    float s = 0.f;
    #pragma unroll
    for (int k = 0; k < 16; ++k) {
      int j = l + 32 * k;
      s += b2f(a.Mb[(size_t)c * CCH + j]) * a.sums[j];
    }
    s += __shfl_down(s, 16, 32);
    s += __shfl_down(s, 8, 32);
    s += __shfl_down(s, 4, 32);
    s += __shfl_down(s, 2, 32);
    s += __shfl_down(s, 1, 32);
    if (l == 0) a.mconst[c] = (0.8f * a.sums[512 + c] - s) * (1.f / (float)NPIX);
  }
  #undef TILE_IDX
}

// ====================== legacy fallback kernels (used only if coop launch fails)
__global__ __launch_bounds__(256) void gram_reduce(const float* __restrict__ Gp,
                                                   const float* __restrict__ sums,
                                                   float* __restrict__ cov,
                                                   float* __restrict__ rowsum) {
  int idx = blockIdx.x * 256 + threadIdx.x;
  int b = idx >> 18;
  int ij = idx & (MS - 1);
  int i = ij >> 9, j = ij & 511;
  int pair = ((i >> 7) << 2) | (j >> 7);
  int lij = ((i & 127) << 7) | (j & 127);
  size_t base = ((size_t)(b * 16) * 16 + pair) * 16384 + lij;
  float g = 0.f;
  #pragma unroll
  for (int kc = 0; kc < 16; ++kc)
    g += Gp[base + (size_t)kc * (16 * 16384)];
  const float* s = sums + b * CCH;
  float v = (g - s[i] * s[j] * (1.f / (float)NPIX)) * (1.f / (float)(NPIX - 1));
  if (i == j) v += 1e-8f;
  cov[idx] = v;
  __shared__ float red[256];
  int t = threadIdx.x;
  red[t] = fabsf(v);
  __syncthreads();
  for (int st = 128; st > 0; st >>= 1) {
    if (t < st) red[t] += red[t + st];
    __syncthreads();
  }
  if (t == 0) atomicAdd(&rowsum[b * CCH + i], red[0]);
}

__global__ __launch_bounds__(256) void nsinit_k(const float* __restrict__ cov,
                                                const float* __restrict__ rowsum,
                                                float* __restrict__ snorm,
                                                float* __restrict__ coef,
                                                u16* __restrict__ Anh,
                                                u16* __restrict__ Anl,
                                                u16* __restrict__ Z0) {
  __shared__ float red[256];
  int tid = threadIdx.x, blk = blockIdx.x;
  float m = fmaxf(rowsum[tid], rowsum[tid + 256]);
  red[tid] = m; __syncthreads();
  for (int s = 128; s > 0; s >>= 1) {
    if (tid < s) red[tid] = fmaxf(red[tid], red[tid + s]);
    __syncthreads();
  }
  float snc = red[0]; __syncthreads();
  m = fmaxf(rowsum[512 + tid], rowsum[768 + tid]);
  red[tid] = m; __syncthreads();
  for (int s = 128; s > 0; s >>= 1) {
    if (tid < s) red[tid] = fmaxf(red[tid], red[tid + s]);
    __syncthreads();
  }
  float sns = red[0];
  if (blk == 0 && tid == 0) {
    snorm[0] = snc; snorm[1] = sns;
    coef[0] = 0.8f * sqrtf(sns / snc);
  }
  int idx = blk * 256 + tid;
  int b = idx >> 18;
  int ij = idx & (MS - 1);
  int diag = (ij >> 9) == (ij & 511);
  float av = cov[idx] * (b ? 1.f / sns : 1.f / snc);
  u16 hi = f2bf(av);
  Anh[idx] = hi;
  Anl[idx] = f2bf(av - b2f(hi));
  float t0 = (diag ? 3.f - av : -av) * 0.70710678f;
  Z0[idx] = f2bf(t0);
}

struct MM16 {
  const u16* A[4];
  const u16* B[4];
  void* D[4];
  float scale, diag;
  int outFp32;
};

__global__ __launch_bounds__(256) void mm16_k(MM16 args) {
  int z = blockIdx.z;
  int bi = blockIdx.y, bj = blockIdx.x;
  __shared__ u16 smem[16384];
  mm_step(args.A[z], args.B[z], args.D[z], args.scale, args.diag, args.outFp32,
          smem, threadIdx.x, bi, bj);
}

__global__ __launch_bounds__(256) void symsplit_k(const float* __restrict__ src,
                                                  u16* __restrict__ hi,
                                                  u16* __restrict__ lo) {
  int b = blockIdx.y;
  int ij = blockIdx.x * 256 + threadIdx.x;
  int i = ij >> 9, j = ij & 511;
  size_t base = (size_t)b * MS;
  float v = 0.5f * (src[base + ij] + src[base + (size_t)j * CCH + i]);
  u16 h = f2bf(v);
  hi[base + ij] = h;
  lo[base + ij] = f2bf(v - b2f(h));
}

struct MMS {
  const u16 *Ah[4], *Al[4], *Bh[4], *Bl[4];
  const u16 *Eh[4], *El[4];
  u16 *Dh[4], *Dl[4];
  float *D32[4];
  u16 *Db[4];
  float scale, beta;
  const float* coefPtr;
};

__global__ __launch_bounds__(256) void mmsplit_k(MMS args) {
  int z = blockIdx.z;
  int bi = blockIdx.y, bj = blockIdx.x;
  __shared__ u16 smem[32768];
  float sc = args.scale;
  if (args.coefPtr) sc *= *args.coefPtr;
  mms_step(args.Ah[z], args.Al[z], args.Bh[z], args.Bl[z],
           args.Eh[z], args.El[z], args.beta,
           args.Dh[z], args.Dl[z], args.D32[z], args.Db[z],
           sc, smem, threadIdx.x, bi, bj);
}

__global__ __launch_bounds__(256) void mconst_k(const u16* __restrict__ Mb,
                                                const float* __restrict__ sums,
                                                float* __restrict__ mconst) {
  int c = blockIdx.x * 8 + (threadIdx.x >> 5);
  int l = threadIdx.x & 31;
  float s = 0.f;
  #pragma unroll
  for (int k = 0; k < 16; ++k) {
    int j = l + 32 * k;
    s += b2f(Mb[(size_t)c * CCH + j]) * sums[j];
  }
  s += __shfl_down(s, 16, 32);
  s += __shfl_down(s, 8, 32);
  s += __shfl_down(s, 4, 32);
  s += __shfl_down(s, 2, 32);
  s += __shfl_down(s, 1, 32);
  if (l == 0) mconst[c] = (0.8f * sums[512 + c] - s) * (1.f / (float)NPIX);
}

// ================= apply: out = fcb @ M^T + mconst + 0.2 X   (128-tiles, Kt=64 dbuf)
__global__ __launch_bounds__(256) void apply_mfma(const u16* __restrict__ fcb,
                                                  const u16* __restrict__ Mb,
                                                  const float* __restrict__ mconst,
                                                  const float* __restrict__ X,
                                                  float* __restrict__ out) {
  int bi = blockIdx.y;    // n tile (0..127)
  int bj = blockIdx.x;    // c tile (0..3)
  __shared__ u16 As[2][128 * 64];
  __shared__ u16 Bs[2][128 * 64];
  int tid = threadIdx.x, w = tid >> 6, lane = tid & 63;
  int qm = w & 1, qn = w >> 1;
  const u16* ssrc = (w < 2) ? fcb + (size_t)(bi * 128) * CCH
                            : Mb + (size_t)(bj * 128) * CCH;
  int rbase = (w & 1) * 64;
  f32x4 acc[4][4];
  #pragma unroll
  for (int t = 0; t < 4; ++t)
    #pragma unroll
    for (int u = 0; u < 4; ++u) acc[t][u] = (f32x4)(0.f);

  #pragma unroll
  for (int i = 0; i < 8; ++i)
    stage8_64(ssrc, CCH, rbase + i * 8, 0, (w < 2) ? As[0] : Bs[0], lane);
  __syncthreads();

  for (int st = 0; st < 8; ++st) {
    int cur = st & 1;
    if (st < 7) {
      #pragma unroll
      for (int i = 0; i < 8; ++i)
        stage8_64(ssrc, CCH, rbase + i * 8, (st + 1) * 64,
                  (w < 2) ? As[cur ^ 1] : Bs[cur ^ 1], lane);
    }
    #pragma unroll
    for (int s = 0; s < 2; ++s) {
      int cl = s * 4 + (lane >> 4);
      bf16x8 a[4], bb[4];
      #pragma unroll
      for (int t = 0; t < 4; ++t) a[t] = fragld64(As[cur], qm * 64 + t * 16 + (lane & 15), cl);
      #pragma unroll
      for (int u = 0; u < 4; ++u) bb[u] = fragld64(Bs[cur], qn * 64 + u * 16 + (lane & 15), cl);
      #pragma unroll
      for (int t = 0; t < 4; ++t)
        #pragma unroll
        for (int u = 0; u < 4; ++u)
          acc[t][u] = __builtin_amdgcn_mfma_f32_16x16x32_bf16(a[t], bb[u], acc[t][u], 0, 0, 0);
    }
    __syncthreads();
  }
  #pragma unroll
  for (int t = 0; t < 4; ++t) {
    int row0 = bi * 128 + qm * 64 + t * 16 + (lane >> 4) * 4;
    #pragma unroll
    for (int u = 0; u < 4; ++u) {
      int col = bj * 128 + qn * 64 + u * 16 + (lane & 15);
      float cst = mconst[col];
      #pragma unroll
      for (int r4 = 0; r4 < 4; ++r4) {
        size_t o = (size_t)(row0 + r4) * CCH + col;
        out[o] = acc[t][u][r4] + cst + 0.2f * X[o];
      }
    }
  }
}

// ================================================================ launcher
extern "C" void kernel_launch(void* const* d_in, const int* in_sizes, int n_in,
                              void* d_out, int out_size, void* d_ws, size_t ws_size,
                              hipStream_t stream) {
  const float* Xc = (const float*)d_in[0];
  const float* Xs = (const float*)d_in[1];
  float* out = (float*)d_out;

  float* f = (float*)d_ws;
  float* sums   = f;                     // 1024
  float* rowsum = f + 1024;              // 1024
  float* cov    = f + 2048 + 2 * MS;     // 2*MS
  float* snorm  = cov + 2 * MS;          // 8
  float* coef   = snorm + 8;             // 8
  float* mconst = coef + 8;              // 512
  float* Zf     = mconst + 512;          // 2*MS (fp32, reused for Zr)

  // Gram split-K partials live in d_out (dead until apply_mfma): 32 MiB exactly.
  float* Gp = (float*)d_out;

  u16* h   = (u16*)(Zf + 2 * MS);
  u16* fct = h;                          // 2*512*16384 u16 (dead after gram)
  u16* fcb = h + (size_t)2 * CCH * NPIX; // 16384*512 u16
  const size_t B2 = 2 * MS;
  u16* Anh  = fct + 0 * B2;
  u16* Anl  = fct + 1 * B2;
  u16* Y1   = fct + 2 * B2;
  u16* Ya   = fct + 3 * B2;
  u16* Z0   = fct + 4 * B2;
  u16* Z1   = fct + 5 * B2;
  u16* Tb   = fct + 6 * B2;
  u16* Zfsh = fct + 7 * B2;
  u16* Zfsl = fct + 8 * B2;
  u16* Ph   = fct + 9 * B2;
  u16* Pl   = fct + 10 * B2;
  u16* Qh   = fct + 11 * B2;
  u16* Ql   = fct + 12 * B2;
  u16* Zrsh = fct + 13 * B2;
  u16* Zrsl = fct + 14 * B2;
  u16* W2h  = fct + 15 * B2;
  u16* W2l  = W2h + MS;
  u16* Mb   = W2l + MS;

  hipMemsetAsync(d_ws, 0, 2048 * sizeof(float), stream);

  prep_k<<<dim3(256, 8, 2), 256, 0, stream>>>(Xc, Xs, sums, fct, fcb);
  gram_part<<<dim3(16, 16, 2), 256, 0, stream>>>(fct, Gp);

  // ---- one cooperative kernel replaces 16 dispatches (greduce .. mconst)
  NSArgs a;
  a.Gp = Gp; a.sums = sums; a.cov = cov; a.rowsum = rowsum;
  a.snorm = snorm; a.coef = coef; a.mconst = mconst; a.Zf = Zf;
  a.Anh = Anh; a.Anl = Anl; a.Y1 = Y1; a.Ya = Ya; a.Z0 = Z0; a.Z1 = Z1; a.Tb = Tb;
  a.Zfsh = Zfsh; a.Zfsl = Zfsl; a.Ph = Ph; a.Pl = Pl; a.Qh = Qh; a.Ql = Ql;
  a.Zrsh = Zrsh; a.Zrsl = Zrsl; a.W2h = W2h; a.W2l = W2l; a.Mb = Mb;
  void* params[1] = { (void*)&a };
  hipError_t ce = hipLaunchCooperativeKernel((const void*)ns_chain,
                                             dim3(512), dim3(256),
                                             params, 0, stream);
  if (ce != hipSuccess) {
    (void)hipGetLastError();   // clear; fall back to multi-dispatch path
    gram_reduce<<<2048, 256, 0, stream>>>(Gp, sums, cov, rowsum);
    nsinit_k<<<2048, 256, 0, stream>>>(cov, rowsum, snorm, coef, Anh, Anl, Z0);
    {
      MM16 y1{};
      y1.A[0] = Anh;      y1.B[0] = Z0;      y1.D[0] = Y1;
      y1.A[1] = Anh + MS; y1.B[1] = Z0 + MS; y1.D[1] = Y1 + MS;
      y1.scale = 1.f; y1.diag = 0.f; y1.outFp32 = 0;
      mm16_k<<<dim3(8, 8, 2), 256, 0, stream>>>(y1);
    }
    {
      MM16 t{};
      t.A[0] = Z0;      t.B[0] = Y1;      t.D[0] = Tb;
      t.A[1] = Z0 + MS; t.B[1] = Y1 + MS; t.D[1] = Tb + MS;
      t.scale = -1.f; t.diag = 3.f; t.outFp32 = 0;
      mm16_k<<<dim3(8, 8, 2), 256, 0, stream>>>(t);
    }
    {
      MM16 yz{};
      yz.A[0] = Y1;      yz.B[0] = Tb;      yz.D[0] = Ya;
      yz.A[1] = Y1 + MS; yz.B[1] = Tb + MS; yz.D[1] = Ya + MS;
      yz.A[2] = Tb;      yz.B[2] = Z0;      yz.D[2] = Z1;
      yz.A[3] = Tb + MS; yz.B[3] = Z0 + MS; yz.D[3] = Z1 + MS;
      yz.scale = 0.5f; yz.diag = 0.f; yz.outFp32 = 0;
      mm16_k<<<dim3(8, 8, 4), 256, 0, stream>>>(yz);
    }
    {
      MM16 t{};
      t.A[0] = Z1;      t.B[0] = Ya;      t.D[0] = Tb;
      t.A[1] = Z1 + MS; t.B[1] = Ya + MS; t.D[1] = Tb + MS;
      t.scale = -1.f; t.diag = 3.f; t.outFp32 = 0;
      mm16_k<<<dim3(8, 8, 2), 256, 0, stream>>>(t);
    }
    {
      MM16 yz{};
      yz.A[0] = Ya;      yz.B[0] = Tb;      yz.D[0] = Y1;
      yz.A[1] = Ya + MS; yz.B[1] = Tb + MS; yz.D[1] = Y1 + MS;
      yz.A[2] = Tb;      yz.B[2] = Z1;      yz.D[2] = Z0;
      yz.A[3] = Tb + MS; yz.B[3] = Z1 + MS; yz.D[3] = Z0 + MS;
      yz.scale = 0.5f; yz.diag = 0.f; yz.outFp32 = 0;
      mm16_k<<<dim3(8, 8, 4), 256, 0, stream>>>(yz);
    }
    {
      MM16 t{};
      t.A[0] = Z0;      t.B[0] = Y1;      t.D[0] = Tb;
      t.A[1] = Z0 + MS; t.B[1] = Y1 + MS; t.D[1] = Tb + MS;
      t.scale = -1.f; t.diag = 3.f; t.outFp32 = 0;
      mm16_k<<<dim3(8, 8, 2), 256, 0, stream>>>(t);
    }
    {
      MM16 zf{};
      zf.A[0] = Tb;      zf.B[0] = Z0;      zf.D[0] = Zf;
      zf.A[1] = Tb + MS; zf.B[1] = Z0 + MS; zf.D[1] = Zf + MS;
      zf.scale = 0.5f; zf.diag = 0.f; zf.outFp32 = 1;
      mm16_k<<<dim3(8, 8, 2), 256, 0, stream>>>(zf);
    }
    symsplit_k<<<dim3(1024, 2), 256, 0, stream>>>(Zf, Zfsh, Zfsl);
    MMS pq{};
    for (int b = 0; b < 2; ++b) {
      pq.Ah[b] = Zfsh + b * MS; pq.Al[b] = Zfsl + b * MS;
      pq.Bh[b] = Anh + b * MS;  pq.Bl[b] = Anl + b * MS;
      pq.Dh[b] = Ph + b * MS;   pq.Dl[b] = Pl + b * MS;
      pq.Ah[2 + b] = Zfsh + b * MS; pq.Al[2 + b] = Zfsl + b * MS;
      pq.Bh[2 + b] = Zfsh + b * MS; pq.Bl[2 + b] = Zfsl + b * MS;
      pq.Dh[2 + b] = Qh + b * MS;   pq.Dl[2 + b] = Ql + b * MS;
    }
    pq.scale = 1.f;
    mmsplit_k<<<dim3(8, 8, 4), 256, 0, stream>>>(pq);
    MMS zr{};
    for (int b = 0; b < 2; ++b) {
      zr.Ah[b] = Ph + b * MS;   zr.Al[b] = Pl + b * MS;
      zr.Bh[b] = Qh + b * MS;   zr.Bl[b] = Ql + b * MS;
      zr.Eh[b] = Zfsh + b * MS; zr.El[b] = Zfsl + b * MS;
      zr.D32[b] = Zf + b * MS;
    }
    zr.scale = -0.5f; zr.beta = 1.5f;
    mmsplit_k<<<dim3(8, 8, 2), 256, 0, stream>>>(zr);
    symsplit_k<<<dim3(1024, 2), 256, 0, stream>>>(Zf, Zrsh, Zrsl);
    MMS wv{};
    wv.Ah[0] = Anh + MS;  wv.Al[0] = Anl + MS;
    wv.Bh[0] = Zrsh + MS; wv.Bl[0] = Zrsl + MS;
    wv.Dh[0] = W2h; wv.Dl[0] = W2l;
    wv.scale = 1.f;
    mmsplit_k<<<dim3(8, 8, 1), 256, 0, stream>>>(wv);
    MMS mv{};
    mv.Ah[0] = W2h;  mv.Al[0] = W2l;
    mv.Bh[0] = Zrsh; mv.Bl[0] = Zrsl;
    mv.Db[0] = Mb;
    mv.scale = 1.f; mv.coefPtr = coef;
    mmsplit_k<<<dim3(8, 8, 1), 256, 0, stream>>>(mv);
    mconst_k<<<64, 256, 0, stream>>>(Mb, sums, mconst);
  }

  apply_mfma<<<dim3(4, 128), 256, 0, stream>>>(fcb, Mb, mconst, Xc, out);
}